// Round 16
// baseline (165.359 us; speedup 1.0000x reference)
//
#include <hip/hip_runtime.h>

// Problem constants
#define BB 32
#define CC 24
#define SSIDE 7
#define NN 49          // objects
#define DD 26          // C+2
#define QQ 2472
#define RN 256
#define NPQ 2401       // 49*49
#define BM 64          // rows per tile in g-kernel
#define NT2 38         // ceil(2401/64) row-tiles per batch
#define NSUB 16        // blocks per batch in k_g_mfma
#define NJ 24          // qv k-chunks (2472 = 24*103)
#define KCH 103

typedef float  f32x4  __attribute__((ext_vector_type(4)));
typedef short  short8 __attribute__((ext_vector_type(8)));
typedef __bf16 bfv8   __attribute__((ext_vector_type(8)));

// ws layout (float offsets), all disjoint.
#define A2_OFF   0                          // [32][49][256] f32
#define BJ_OFF   (A2_OFF + BB*NN*RN)        // [32][49][256] f32 (b1 included, qv NOT)
#define WGT_OFF  (BJ_OFF + BB*NN*RN)        // WgT bf16 [256][256] = 32768 f32 slots
#define PART_OFF (WGT_OFF + 32768)          // [32][16][256] f32
#define QV_OFF   (PART_OFF + BB*NSUB*RN)    // [32][24][256] f32

static __device__ __forceinline__ short f2bf(float f) {
    return __builtin_bit_cast(short, (__bf16)f);
}

// XCD-affinity decode: bid = q*8 + xcd (XCD assumed round-robin on bid%8;
// wrong assumption = perf-neutral, never incorrect). b = xcd + 8*(q&3) puts
// all producers and consumers of batch b on XCD b%8.

// ---------------------------------------------------------------------------
// Kernel 1 (3 independent roles, one launch):
//   blocks [0, 768)      : Qv partials  (b on XCD b%8)
//   blocks [768, 784)    : Wg transpose+bf16 via LDS (64x64 tiles)
//   blocks [784, 2352)   : A2/Bj' build (b on XCD b%8)
// ---------------------------------------------------------------------------
__global__ __launch_bounds__(256) void k_prep(const float* __restrict__ x,
                                              const float* __restrict__ qst,
                                              const float* __restrict__ W1,
                                              const float* __restrict__ b1,
                                              const float* __restrict__ Wg,
                                              float* __restrict__ ws) {
    const int bid = blockIdx.x;
    if (bid < BB * NJ) {
        const int xcd = bid & 7, qq = bid >> 3;          // qq 0..95
        const int b = xcd + 8 * (qq & 3), j = qq >> 2;   // j 0..23
        const int r = threadIdx.x;
        const int k0 = j * KCH;
        const float* q = qst + b * QQ + k0;
        const float* w = W1 + (2 * DD + k0) * RN + r;
        float acc = 0.f;
        #pragma unroll 4
        for (int k = 0; k < KCH; ++k)
            acc += q[k] * w[k * RN];
        ws[QV_OFF + (b * NJ + j) * RN + r] = acc;
    } else if (bid < BB * NJ + 16) {
        const int t = bid - BB * NJ;            // 0..15
        const int kt = (t >> 2) * 64, nt = (t & 3) * 64;
        const int tx = threadIdx.x & 63, ty = threadIdx.x >> 6;
        __shared__ short lds[64 * 65];
        short* wgt = (short*)(ws + WGT_OFF);
        #pragma unroll
        for (int i = 0; i < 16; ++i) {
            const int k = ty + i * 4;
            lds[tx * 65 + k] = f2bf(Wg[(kt + k) * RN + nt + tx]);
        }
        __syncthreads();
        #pragma unroll
        for (int i = 0; i < 16; ++i) {
            const int n = ty + i * 4;
            wgt[(nt + n) * RN + kt + tx] = lds[n * 65 + tx];
        }
    } else {
        const int u = bid - (BB * NJ + 16);
        const int xcd = u & 7, qq = u >> 3;              // qq 0..195
        const int b = xcd + 8 * (qq & 3), n = qq >> 2;   // n 0..48
        const int r = threadIdx.x;
        float a2 = 0.f, bj = b1[r];
        #pragma unroll
        for (int d = 0; d < DD; ++d) {
            float xv;
            if (d < CC)            xv = x[(b * CC + d) * NN + n];
            else if (d == CC)      xv = (float)(n / SSIDE) * (1.0f / 6.0f);
            else                   xv = (float)(n % SSIDE) * (1.0f / 6.0f);
            a2 += xv * W1[d * RN + r];
            bj += xv * W1[(DD + d) * RN + r];
        }
        ws[A2_OFF + (b * NN + n) * RN + r] = a2;
        ws[BJ_OFF + (b * NN + n) * RN + r] = bj;
    }
}

// ---------------------------------------------------------------------------
// Kernel 2: multi-tile MFMA g-layers. Grid 512 = 16 sub-blocks x 32 batches
// (XCD affinity). Block (b, sub) processes tiles t = sub, sub+16, ... (<38):
// 2-3 tiles. Qv and Wg^T fragments loaded ONCE per block; h-tile double-
// buffered so tile i+1's staging (between layer-1 and layer-2 of tile i)
// hides L2 latency under MFMA. 2 barriers per tile.
// k-convention for A/B slots: k = ks*32 + hi*8 + i (same on both operands).
// C/D layout (measured m89): col = lane&15, row = (lane>>4)*4 + reg.
// ---------------------------------------------------------------------------
__global__ __launch_bounds__(256, 2) void k_g_mfma2(const float* __restrict__ bg,
                                                    float* __restrict__ ws) {
    const int bid = blockIdx.x;
    const int xcd = bid & 7, q5 = bid >> 3;              // q5 0..63
    const int b = xcd + 8 * (q5 & 3), sub = q5 >> 2;     // sub 0..15
    const int tid = threadIdx.x;
    const int lane = tid & 63, w = tid >> 6;
    const int lo = lane & 15, hi = lane >> 4;
    const float* A2 = ws + A2_OFF + b * NN * RN;
    const float* Bj = ws + BJ_OFF + b * NN * RN;
    const short* wgt = (const short*)(ws + WGT_OFF);

    __shared__ short8 hbuf[2][BM * 32];     // [buf][row][chunk^(row&7)], 2x32 KB
    __shared__ float qvs[RN];
    const int njobs = (NT2 - sub + NSUB - 1) / NSUB;     // 2 or 3

    // ---- stage Qv[b] into LDS (sum of 24 partials), once per block ----
    {
        float qv = 0.f;
        #pragma unroll 4
        for (int j = 0; j < NJ; ++j)
            qv += ws[QV_OFF + (b * NJ + j) * RN + tid];
        qvs[tid] = qv;
    }

    // ---- load Wg^T B-fragments for this wave's 64 cols, once per block ----
    const int wcol0 = w * 64;
    bfv8 bfr[4][8];
    #pragma unroll
    for (int ct = 0; ct < 4; ++ct) {
        const int n = wcol0 + ct * 16 + lo;
        #pragma unroll
        for (int ks = 0; ks < 8; ++ks)
            bfr[ct][ks] = __builtin_bit_cast(bfv8,
                *(const short8*)(wgt + n * RN + ks * 32 + hi * 8));
    }
    float bgv[4];
    #pragma unroll
    for (int ct = 0; ct < 4; ++ct)
        bgv[ct] = bg[wcol0 + ct * 16 + lo];

    __syncthreads();                        // qvs ready

    // ---- staging macro: tile -> hbuf[bufi] (swizzled bf16, relu(a+b+qv)) ----
    #define STAGE_TILE(TSTART, BUFI)                                           \
    do {                                                                       \
        const int brow0_ = (TSTART) * BM;                                      \
        _Pragma("unroll")                                                      \
        for (int it = 0; it < 8; ++it) {                                       \
            const int cid = it * 256 + tid;                                    \
            const int row = cid >> 5, chunk = cid & 31;                        \
            const int grow = brow0_ + row;                                     \
            short8 v8 = (short8)0;                                             \
            if (grow < NPQ) {                                                  \
                const int p = grow / NN, qo = grow - p * NN;                   \
                const float4 a0 = *(const float4*)(A2 + qo * RN + chunk * 8);  \
                const float4 a1 = *(const float4*)(A2 + qo * RN + chunk * 8 + 4);\
                const float4 b0 = *(const float4*)(Bj + p * RN + chunk * 8);   \
                const float4 b1v = *(const float4*)(Bj + p * RN + chunk * 8 + 4);\
                const float* qc = qvs + chunk * 8;                             \
                v8[0] = f2bf(fmaxf(a0.x + b0.x + qc[0], 0.f));                 \
                v8[1] = f2bf(fmaxf(a0.y + b0.y + qc[1], 0.f));                 \
                v8[2] = f2bf(fmaxf(a0.z + b0.z + qc[2], 0.f));                 \
                v8[3] = f2bf(fmaxf(a0.w + b0.w + qc[3], 0.f));                 \
                v8[4] = f2bf(fmaxf(a1.x + b1v.x + qc[4], 0.f));                \
                v8[5] = f2bf(fmaxf(a1.y + b1v.y + qc[5], 0.f));                \
                v8[6] = f2bf(fmaxf(a1.z + b1v.z + qc[6], 0.f));                \
                v8[7] = f2bf(fmaxf(a1.w + b1v.w + qc[7], 0.f));                \
            }                                                                  \
            hbuf[BUFI][row * 32 + (chunk ^ (row & 7))] = v8;                   \
        }                                                                      \
    } while (0)

    STAGE_TILE(sub, 0);                     // prologue: first tile -> buf0
    __syncthreads();

    float cs[4] = {0.f, 0.f, 0.f, 0.f};     // colsum accumulator across tiles
    f32x4 acc[4][4];                        // [ct][rt]

    for (int i = 0; i < njobs; ++i) {
        const int cur = i & 1;
        const int tcur = sub + i * NSUB;
        short8* hbc = hbuf[cur];
        short* hb = (short*)hbc;

        // ---- g layer 1 on buf[cur] ----
        #pragma unroll
        for (int ct = 0; ct < 4; ++ct)
            #pragma unroll
            for (int rt = 0; rt < 4; ++rt)
                acc[ct][rt] = (f32x4){0.f, 0.f, 0.f, 0.f};
        #pragma unroll
        for (int rt = 0; rt < 4; ++rt) {
            const int row = rt * 16 + lo;
            bfv8 afr[8];
            #pragma unroll
            for (int ks = 0; ks < 8; ++ks)
                afr[ks] = __builtin_bit_cast(bfv8,
                    hbc[row * 32 + ((ks * 4 + hi) ^ (row & 7))]);
            #pragma unroll
            for (int ks = 0; ks < 8; ++ks)
                #pragma unroll
                for (int ct = 0; ct < 4; ++ct)
                    acc[ct][rt] = __builtin_amdgcn_mfma_f32_16x16x32_bf16(
                        afr[ks], bfr[ct][ks], acc[ct][rt], 0, 0, 0);
        }
        __syncthreads();                    // all h1 reads of buf[cur] done

        // ---- bias+relu, h2 -> buf[cur] (swizzled bf16) ----
        #pragma unroll
        for (int ct = 0; ct < 4; ++ct) {
            const int n = wcol0 + ct * 16 + lo;
            #pragma unroll
            for (int rt = 0; rt < 4; ++rt) {
                #pragma unroll
                for (int r = 0; r < 4; ++r) {
                    const int row = rt * 16 + hi * 4 + r;
                    const float v = fmaxf(acc[ct][rt][r] + bgv[ct], 0.f);
                    hb[row * 256 + (((n >> 3) ^ (row & 7)) << 3) + (n & 7)] = f2bf(v);
                }
            }
        }

        // ---- stage NEXT tile -> buf[cur^1] (overlaps h2 writeback wait) ----
        if (i + 1 < njobs)
            STAGE_TILE(tcur + NSUB, cur ^ 1);
        __syncthreads();                    // h2 ready AND next tile ready

        // ---- g layer 2 on buf[cur] + masked colsum ----
        #pragma unroll
        for (int ct = 0; ct < 4; ++ct)
            #pragma unroll
            for (int rt = 0; rt < 4; ++rt)
                acc[ct][rt] = (f32x4){0.f, 0.f, 0.f, 0.f};
        #pragma unroll
        for (int rt = 0; rt < 4; ++rt) {
            const int row = rt * 16 + lo;
            bfv8 afr[8];
            #pragma unroll
            for (int ks = 0; ks < 8; ++ks)
                afr[ks] = __builtin_bit_cast(bfv8,
                    hbc[row * 32 + ((ks * 4 + hi) ^ (row & 7))]);
            #pragma unroll
            for (int ks = 0; ks < 8; ++ks)
                #pragma unroll
                for (int ct = 0; ct < 4; ++ct)
                    acc[ct][rt] = __builtin_amdgcn_mfma_f32_16x16x32_bf16(
                        afr[ks], bfr[ct][ks], acc[ct][rt], 0, 0, 0);
        }
        const int brow0 = tcur * BM;
        #pragma unroll
        for (int ct = 0; ct < 4; ++ct) {
            #pragma unroll
            for (int rt = 0; rt < 4; ++rt) {
                #pragma unroll
                for (int r = 0; r < 4; ++r) {
                    const int grow = brow0 + rt * 16 + hi * 4 + r;
                    const float v = fmaxf(acc[ct][rt][r] + bgv[ct], 0.f);
                    cs[ct] += (grow < NPQ) ? v : 0.f;
                }
            }
        }
        // next iter's layer-1 reads buf[cur^1] (staged, barriered); its
        // h2/stage writes happen only after its own first barrier, which
        // orders them after this iter's layer-2 reads.
    }
    #undef STAGE_TILE

    // ---- cross-lane reduce, store per-(b,sub) partial ----
    #pragma unroll
    for (int ct = 0; ct < 4; ++ct) {
        float v = cs[ct];
        v += __shfl_xor(v, 16);
        v += __shfl_xor(v, 32);
        if (hi == 0)
            ws[PART_OFF + (b * NSUB + sub) * RN + wcol0 + ct * 16 + lo] = v;
    }
}

// ---------------------------------------------------------------------------
// Kernel 3: reduce partials -> x_g[b], then two f layers, write out.
// Block b lands on XCD b%8 (bid = b), matching PART[b]'s producer XCD.
// ---------------------------------------------------------------------------
__global__ void k_f_reduce(const float* __restrict__ Wf,
                           const float* __restrict__ bf,
                           const float* __restrict__ ws,
                           float* __restrict__ out) {
    const int b = blockIdx.x, r = threadIdx.x;
    __shared__ float xs[RN];
    float xg = 0.f;
    #pragma unroll
    for (int t = 0; t < NSUB; ++t)
        xg += ws[PART_OFF + (b * NSUB + t) * RN + r];
    xs[r] = xg;
    __syncthreads();

    float v = 0.f;
    #pragma unroll
    for (int layer = 0; layer < 2; ++layer) {
        float acc = bf[r];
        for (int s = 0; s < RN; ++s)
            acc += xs[s] * Wf[s * RN + r];
        v = fmaxf(acc, 0.f);
        __syncthreads();
        xs[r] = v;
        __syncthreads();
    }
    out[b * RN + r] = v;
}

// ---------------------------------------------------------------------------
extern "C" void kernel_launch(void* const* d_in, const int* in_sizes, int n_in,
                              void* d_out, int out_size, void* d_ws, size_t ws_size,
                              hipStream_t stream) {
    const float* x   = (const float*)d_in[0];
    const float* qst = (const float*)d_in[1];
    const float* W1  = (const float*)d_in[2];
    const float* b1  = (const float*)d_in[3];
    const float* Wg  = (const float*)d_in[4];
    const float* bg  = (const float*)d_in[5];
    const float* Wf  = (const float*)d_in[6];
    const float* bf  = (const float*)d_in[7];
    float* out = (float*)d_out;
    float* ws  = (float*)d_ws;

    k_prep      <<<BB * NJ + 16 + BB * NN, RN, 0, stream>>>(x, qst, W1, b1, Wg, ws);
    k_g_mfma2   <<<NSUB * BB, RN, 0, stream>>>(bg, ws);
    k_f_reduce  <<<BB, RN, 0, stream>>>(Wf, bf, ws, out);
}

// Round 17
// 144.240 us; speedup vs baseline: 1.1464x; 1.1464x over previous
//
#include <hip/hip_runtime.h>

// Problem constants
#define BB 32
#define CC 24
#define SSIDE 7
#define NN 49          // objects
#define DD 26          // C+2
#define QQ 2472
#define RN 256
#define NPQ 2401       // 49*49
#define BM 64          // rows per tile in g-kernel
#define NT2 38         // ceil(2401/64) row-tiles per batch
#define NSUB 16        // blocks per batch in k_g_mfma
#define NJ 24          // qv k-chunks (2472 = 24*103)
#define KCH 103

typedef float  f32x4  __attribute__((ext_vector_type(4)));
typedef short  short8 __attribute__((ext_vector_type(8)));
typedef __bf16 bfv8   __attribute__((ext_vector_type(8)));

// ws layout (float offsets), all disjoint.
#define A2_OFF   0                          // [32][49][256] f32
#define BJ_OFF   (A2_OFF + BB*NN*RN)        // [32][49][256] f32 (b1 included, qv NOT)
#define WGT_OFF  (BJ_OFF + BB*NN*RN)        // WgT bf16 [256][256] = 32768 f32 slots
#define PART_OFF (WGT_OFF + 32768)          // [32][16][256] f32
#define QV_OFF   (PART_OFF + BB*NSUB*RN)    // [32][24][256] f32

static __device__ __forceinline__ short f2bf(float f) {
    return __builtin_bit_cast(short, (__bf16)f);
}

// XCD-affinity decode: bid = q*8 + xcd (XCD assumed round-robin on bid%8;
// wrong assumption = perf-neutral, never incorrect). b = xcd + 8*(q&3) puts
// all producers and consumers of batch b on XCD b%8.

// ---------------------------------------------------------------------------
// Kernel 1 (3 independent roles, one launch):
//   blocks [0, 768)      : Qv partials  (b on XCD b%8)
//   blocks [768, 784)    : Wg transpose+bf16 via LDS (64x64 tiles)
//   blocks [784, 2352)   : A2/Bj' build (b on XCD b%8)
// ---------------------------------------------------------------------------
__global__ __launch_bounds__(256) void k_prep(const float* __restrict__ x,
                                              const float* __restrict__ qst,
                                              const float* __restrict__ W1,
                                              const float* __restrict__ b1,
                                              const float* __restrict__ Wg,
                                              float* __restrict__ ws) {
    const int bid = blockIdx.x;
    if (bid < BB * NJ) {
        const int xcd = bid & 7, qq = bid >> 3;          // qq 0..95
        const int b = xcd + 8 * (qq & 3), j = qq >> 2;   // j 0..23
        const int r = threadIdx.x;
        const int k0 = j * KCH;
        const float* q = qst + b * QQ + k0;
        const float* w = W1 + (2 * DD + k0) * RN + r;
        float acc = 0.f;
        #pragma unroll 4
        for (int k = 0; k < KCH; ++k)
            acc += q[k] * w[k * RN];
        ws[QV_OFF + (b * NJ + j) * RN + r] = acc;
    } else if (bid < BB * NJ + 16) {
        const int t = bid - BB * NJ;            // 0..15
        const int kt = (t >> 2) * 64, nt = (t & 3) * 64;
        const int tx = threadIdx.x & 63, ty = threadIdx.x >> 6;
        __shared__ short lds[64 * 65];
        short* wgt = (short*)(ws + WGT_OFF);
        #pragma unroll
        for (int i = 0; i < 16; ++i) {
            const int k = ty + i * 4;
            lds[tx * 65 + k] = f2bf(Wg[(kt + k) * RN + nt + tx]);
        }
        __syncthreads();
        #pragma unroll
        for (int i = 0; i < 16; ++i) {
            const int n = ty + i * 4;
            wgt[(nt + n) * RN + kt + tx] = lds[n * 65 + tx];
        }
    } else {
        const int u = bid - (BB * NJ + 16);
        const int xcd = u & 7, qq = u >> 3;              // qq 0..195
        const int b = xcd + 8 * (qq & 3), n = qq >> 2;   // n 0..48
        const int r = threadIdx.x;
        float a2 = 0.f, bj = b1[r];
        #pragma unroll
        for (int d = 0; d < DD; ++d) {
            float xv;
            if (d < CC)            xv = x[(b * CC + d) * NN + n];
            else if (d == CC)      xv = (float)(n / SSIDE) * (1.0f / 6.0f);
            else                   xv = (float)(n % SSIDE) * (1.0f / 6.0f);
            a2 += xv * W1[d * RN + r];
            bj += xv * W1[(DD + d) * RN + r];
        }
        ws[A2_OFF + (b * NN + n) * RN + r] = a2;
        ws[BJ_OFF + (b * NN + n) * RN + r] = bj;
    }
}

// ---------------------------------------------------------------------------
// Kernel 2: multi-tile MFMA g-layers. Grid 512 = 16 sub-blocks x 32 batches
// (XCD affinity). Block (b, sub) processes tiles t = sub, sub+16, ... (<38):
// 2-3 tiles. Qv and Wg^T fragments loaded ONCE per block; h-tile double-
// buffered so tile i+1's staging (between layer-1 and layer-2 of tile i)
// hides L2 latency under MFMA. 2 barriers per tile.
// NOTE: __launch_bounds__(256) WITHOUT min-waves arg — the (256,2) variant
// capped VGPR at 128 and spilled ~80 dwords/thread (round 16: FETCH/WRITE
// ballooned to 41 MB each, MfmaUtil 9%). Live set is bfr[4][8]=128 VGPR +
// acc=64 + staging; needs ~220 VGPR. LDS 66.5 KB still allows 2 blocks/CU.
// k-convention for A/B slots: k = ks*32 + hi*8 + i (same on both operands).
// C/D layout (measured m89): col = lane&15, row = (lane>>4)*4 + reg.
// ---------------------------------------------------------------------------
__global__ __launch_bounds__(256) void k_g_mfma2(const float* __restrict__ bg,
                                                 float* __restrict__ ws) {
    const int bid = blockIdx.x;
    const int xcd = bid & 7, q5 = bid >> 3;              // q5 0..63
    const int b = xcd + 8 * (q5 & 3), sub = q5 >> 2;     // sub 0..15
    const int tid = threadIdx.x;
    const int lane = tid & 63, w = tid >> 6;
    const int lo = lane & 15, hi = lane >> 4;
    const float* A2 = ws + A2_OFF + b * NN * RN;
    const float* Bj = ws + BJ_OFF + b * NN * RN;
    const short* wgt = (const short*)(ws + WGT_OFF);

    __shared__ short8 hbuf[2][BM * 32];     // [buf][row][chunk^(row&7)], 2x32 KB
    __shared__ float qvs[RN];
    const int njobs = (NT2 - sub + NSUB - 1) / NSUB;     // 2 or 3

    // ---- stage Qv[b] into LDS (sum of 24 partials), once per block ----
    {
        float qv = 0.f;
        #pragma unroll 4
        for (int j = 0; j < NJ; ++j)
            qv += ws[QV_OFF + (b * NJ + j) * RN + tid];
        qvs[tid] = qv;
    }

    // ---- load Wg^T B-fragments for this wave's 64 cols, once per block ----
    const int wcol0 = w * 64;
    bfv8 bfr[4][8];
    #pragma unroll
    for (int ct = 0; ct < 4; ++ct) {
        const int n = wcol0 + ct * 16 + lo;
        #pragma unroll
        for (int ks = 0; ks < 8; ++ks)
            bfr[ct][ks] = __builtin_bit_cast(bfv8,
                *(const short8*)(wgt + n * RN + ks * 32 + hi * 8));
    }
    float bgv[4];
    #pragma unroll
    for (int ct = 0; ct < 4; ++ct)
        bgv[ct] = bg[wcol0 + ct * 16 + lo];

    __syncthreads();                        // qvs ready

    // ---- staging macro: tile -> hbuf[bufi] (swizzled bf16, relu(a+b+qv)) ----
    #define STAGE_TILE(TSTART, BUFI)                                           \
    do {                                                                       \
        const int brow0_ = (TSTART) * BM;                                      \
        _Pragma("unroll")                                                      \
        for (int it = 0; it < 8; ++it) {                                       \
            const int cid = it * 256 + tid;                                    \
            const int row = cid >> 5, chunk = cid & 31;                        \
            const int grow = brow0_ + row;                                     \
            short8 v8 = (short8)0;                                             \
            if (grow < NPQ) {                                                  \
                const int p = grow / NN, qo = grow - p * NN;                   \
                const float4 a0 = *(const float4*)(A2 + qo * RN + chunk * 8);  \
                const float4 a1 = *(const float4*)(A2 + qo * RN + chunk * 8 + 4);\
                const float4 b0 = *(const float4*)(Bj + p * RN + chunk * 8);   \
                const float4 b1v = *(const float4*)(Bj + p * RN + chunk * 8 + 4);\
                const float* qc = qvs + chunk * 8;                             \
                v8[0] = f2bf(fmaxf(a0.x + b0.x + qc[0], 0.f));                 \
                v8[1] = f2bf(fmaxf(a0.y + b0.y + qc[1], 0.f));                 \
                v8[2] = f2bf(fmaxf(a0.z + b0.z + qc[2], 0.f));                 \
                v8[3] = f2bf(fmaxf(a0.w + b0.w + qc[3], 0.f));                 \
                v8[4] = f2bf(fmaxf(a1.x + b1v.x + qc[4], 0.f));                \
                v8[5] = f2bf(fmaxf(a1.y + b1v.y + qc[5], 0.f));                \
                v8[6] = f2bf(fmaxf(a1.z + b1v.z + qc[6], 0.f));                \
                v8[7] = f2bf(fmaxf(a1.w + b1v.w + qc[7], 0.f));                \
            }                                                                  \
            hbuf[BUFI][row * 32 + (chunk ^ (row & 7))] = v8;                   \
        }                                                                      \
    } while (0)

    STAGE_TILE(sub, 0);                     // prologue: first tile -> buf0
    __syncthreads();

    float cs[4] = {0.f, 0.f, 0.f, 0.f};     // colsum accumulator across tiles
    f32x4 acc[4][4];                        // [ct][rt]

    for (int i = 0; i < njobs; ++i) {
        const int cur = i & 1;
        const int tcur = sub + i * NSUB;
        short8* hbc = hbuf[cur];
        short* hb = (short*)hbc;

        // ---- g layer 1 on buf[cur] ----
        #pragma unroll
        for (int ct = 0; ct < 4; ++ct)
            #pragma unroll
            for (int rt = 0; rt < 4; ++rt)
                acc[ct][rt] = (f32x4){0.f, 0.f, 0.f, 0.f};
        #pragma unroll
        for (int rt = 0; rt < 4; ++rt) {
            const int row = rt * 16 + lo;
            bfv8 afr[8];
            #pragma unroll
            for (int ks = 0; ks < 8; ++ks)
                afr[ks] = __builtin_bit_cast(bfv8,
                    hbc[row * 32 + ((ks * 4 + hi) ^ (row & 7))]);
            #pragma unroll
            for (int ks = 0; ks < 8; ++ks)
                #pragma unroll
                for (int ct = 0; ct < 4; ++ct)
                    acc[ct][rt] = __builtin_amdgcn_mfma_f32_16x16x32_bf16(
                        afr[ks], bfr[ct][ks], acc[ct][rt], 0, 0, 0);
        }
        __syncthreads();                    // all h1 reads of buf[cur] done

        // ---- bias+relu, h2 -> buf[cur] (swizzled bf16) ----
        #pragma unroll
        for (int ct = 0; ct < 4; ++ct) {
            const int n = wcol0 + ct * 16 + lo;
            #pragma unroll
            for (int rt = 0; rt < 4; ++rt) {
                #pragma unroll
                for (int r = 0; r < 4; ++r) {
                    const int row = rt * 16 + hi * 4 + r;
                    const float v = fmaxf(acc[ct][rt][r] + bgv[ct], 0.f);
                    hb[row * 256 + (((n >> 3) ^ (row & 7)) << 3) + (n & 7)] = f2bf(v);
                }
            }
        }

        // ---- stage NEXT tile -> buf[cur^1] (overlaps h2 writeback wait) ----
        if (i + 1 < njobs)
            STAGE_TILE(tcur + NSUB, cur ^ 1);
        __syncthreads();                    // h2 ready AND next tile ready

        // ---- g layer 2 on buf[cur] + masked colsum ----
        #pragma unroll
        for (int ct = 0; ct < 4; ++ct)
            #pragma unroll
            for (int rt = 0; rt < 4; ++rt)
                acc[ct][rt] = (f32x4){0.f, 0.f, 0.f, 0.f};
        #pragma unroll
        for (int rt = 0; rt < 4; ++rt) {
            const int row = rt * 16 + lo;
            bfv8 afr[8];
            #pragma unroll
            for (int ks = 0; ks < 8; ++ks)
                afr[ks] = __builtin_bit_cast(bfv8,
                    hbc[row * 32 + ((ks * 4 + hi) ^ (row & 7))]);
            #pragma unroll
            for (int ks = 0; ks < 8; ++ks)
                #pragma unroll
                for (int ct = 0; ct < 4; ++ct)
                    acc[ct][rt] = __builtin_amdgcn_mfma_f32_16x16x32_bf16(
                        afr[ks], bfr[ct][ks], acc[ct][rt], 0, 0, 0);
        }
        const int brow0 = tcur * BM;
        #pragma unroll
        for (int ct = 0; ct < 4; ++ct) {
            #pragma unroll
            for (int rt = 0; rt < 4; ++rt) {
                #pragma unroll
                for (int r = 0; r < 4; ++r) {
                    const int grow = brow0 + rt * 16 + hi * 4 + r;
                    const float v = fmaxf(acc[ct][rt][r] + bgv[ct], 0.f);
                    cs[ct] += (grow < NPQ) ? v : 0.f;
                }
            }
        }
        // next iter's layer-1 reads buf[cur^1] (staged, barriered); its
        // h2/stage writes happen only after its own first barrier, which
        // orders them after this iter's layer-2 reads.
    }
    #undef STAGE_TILE

    // ---- cross-lane reduce, store per-(b,sub) partial ----
    #pragma unroll
    for (int ct = 0; ct < 4; ++ct) {
        float v = cs[ct];
        v += __shfl_xor(v, 16);
        v += __shfl_xor(v, 32);
        if (hi == 0)
            ws[PART_OFF + (b * NSUB + sub) * RN + wcol0 + ct * 16 + lo] = v;
    }
}

// ---------------------------------------------------------------------------
// Kernel 3: reduce partials -> x_g[b], then two f layers, write out.
// Block b lands on XCD b%8 (bid = b), matching PART[b]'s producer XCD.
// ---------------------------------------------------------------------------
__global__ void k_f_reduce(const float* __restrict__ Wf,
                           const float* __restrict__ bf,
                           const float* __restrict__ ws,
                           float* __restrict__ out) {
    const int b = blockIdx.x, r = threadIdx.x;
    __shared__ float xs[RN];
    float xg = 0.f;
    #pragma unroll
    for (int t = 0; t < NSUB; ++t)
        xg += ws[PART_OFF + (b * NSUB + t) * RN + r];
    xs[r] = xg;
    __syncthreads();

    float v = 0.f;
    #pragma unroll
    for (int layer = 0; layer < 2; ++layer) {
        float acc = bf[r];
        for (int s = 0; s < RN; ++s)
            acc += xs[s] * Wf[s * RN + r];
        v = fmaxf(acc, 0.f);
        __syncthreads();
        xs[r] = v;
        __syncthreads();
    }
    out[b * RN + r] = v;
}

// ---------------------------------------------------------------------------
extern "C" void kernel_launch(void* const* d_in, const int* in_sizes, int n_in,
                              void* d_out, int out_size, void* d_ws, size_t ws_size,
                              hipStream_t stream) {
    const float* x   = (const float*)d_in[0];
    const float* qst = (const float*)d_in[1];
    const float* W1  = (const float*)d_in[2];
    const float* b1  = (const float*)d_in[3];
    const float* Wg  = (const float*)d_in[4];
    const float* bg  = (const float*)d_in[5];
    const float* Wf  = (const float*)d_in[6];
    const float* bf  = (const float*)d_in[7];
    float* out = (float*)d_out;
    float* ws  = (float*)d_ws;

    k_prep      <<<BB * NJ + 16 + BB * NN, RN, 0, stream>>>(x, qst, W1, b1, Wg, ws);
    k_g_mfma2   <<<NSUB * BB, RN, 0, stream>>>(bg, ws);
    k_f_reduce  <<<BB, RN, 0, stream>>>(Wf, bf, ws, out);
}